// Round 1
// baseline (860.054 us; speedup 1.0000x reference)
//
#include <hip/hip_runtime.h>
#include <hip/hip_bf16.h>
#include <math.h>

constexpr int B = 16, S = 2048, D = 128, H = 8, NM = 4;

// ---------------------------------------------------------------------------
// Kernel A: compute f = sigmoid(x@Wf + bf), w = router[:,:,mem_id], then the
// suffix products A_t = prod_{u>t} f_u per (b,h). Writes a[b,h,t] = A_t * w_t
// and Fall[b,h] = prod_t f_t into workspace.
// One block per b; 256 threads; each thread owns 8 consecutive t.
// ---------------------------------------------------------------------------
__global__ __launch_bounds__(256, 1) void scan_kernel(
    const float* __restrict__ x, const float* __restrict__ router,
    const int* __restrict__ mem_id, const float* __restrict__ Wf,
    const float* __restrict__ bfv, float* __restrict__ a_out,
    float* __restrict__ fall_out)
{
    __shared__ float sF[H][S];       // 64 KB
    __shared__ float sC[H][256];     // 8 KB
    __shared__ float sWf[D * H];     // 4 KB

    const int b = blockIdx.x;
    const int tid = threadIdx.x;

    for (int e = tid; e < D * H; e += 256) sWf[e] = Wf[e];
    __syncthreads();

    const int mid = mem_id[0];

    // f for this thread's 8 rows
    for (int u = 0; u < 8; ++u) {
        const int t = tid * 8 + u;
        const float* xr = x + ((size_t)b * S + t) * D;
        float acc[H];
        #pragma unroll
        for (int h = 0; h < H; ++h) acc[h] = 0.f;
        for (int d = 0; d < D; d += 4) {
            const float4 xv = *(const float4*)(xr + d);
            const float* w0 = &sWf[d * H];
            #pragma unroll
            for (int h = 0; h < H; ++h) acc[h] += xv.x * w0[h];
            #pragma unroll
            for (int h = 0; h < H; ++h) acc[h] += xv.y * w0[H + h];
            #pragma unroll
            for (int h = 0; h < H; ++h) acc[h] += xv.z * w0[2 * H + h];
            #pragma unroll
            for (int h = 0; h < H; ++h) acc[h] += xv.w * w0[3 * H + h];
        }
        #pragma unroll
        for (int h = 0; h < H; ++h) {
            const float z = acc[h] + bfv[h];
            sF[h][t] = 1.f / (1.f + expf(-z));
        }
    }
    __syncthreads();

    // per-chunk products
    #pragma unroll
    for (int h = 0; h < H; ++h) {
        float p = 1.f;
        #pragma unroll
        for (int u = 0; u < 8; ++u) p *= sF[h][tid * 8 + u];
        sC[h][tid] = p;
    }
    __syncthreads();

    // Hillis-Steele inclusive SUFFIX scan (product) over 256 chunks, all H at once
    for (int off = 1; off < 256; off <<= 1) {
        float tmp[H];
        #pragma unroll
        for (int h = 0; h < H; ++h)
            tmp[h] = (tid + off < 256) ? sC[h][tid + off] : 1.f;
        __syncthreads();
        #pragma unroll
        for (int h = 0; h < H; ++h) sC[h][tid] *= tmp[h];
        __syncthreads();
    }

    // a[b,h,t] = w_t * (suffix-within-chunk) * (exclusive suffix of later chunks)
    #pragma unroll
    for (int h = 0; h < H; ++h) {
        const float E = (tid < 255) ? sC[h][tid + 1] : 1.f;
        float aa[8];
        float s = 1.f;
        #pragma unroll
        for (int u = 7; u >= 0; --u) {
            aa[u] = s * E;          // prod_{u'>u in chunk} * prod_{chunks>tid}
            s *= sF[h][tid * 8 + u];
        }
        #pragma unroll
        for (int u = 0; u < 8; ++u) {
            const int t = tid * 8 + u;
            const float w = router[((size_t)b * S + t) * NM + mid];
            a_out[((size_t)(b * H + h)) * S + t] = aa[u] * w;
        }
    }

    if (tid == 0) {
        #pragma unroll
        for (int h = 0; h < H; ++h) fall_out[b * H + h] = sC[h][0];
    }
}

// ---------------------------------------------------------------------------
// Kernel B: per (b,h): C = Fall*M0 + sum_t a_t * k_t (x) v_t, fused K/V
// projection. grid = (B*H, 2): t-range split in two for full-CU occupancy,
// combined with fp32 hw atomics onto a zeroed output.
// 153 KB LDS -> 1 block/CU. 256 threads, 8x8 accumulators each.
// ---------------------------------------------------------------------------
__global__ __launch_bounds__(256, 1) void main_kernel(
    const float* __restrict__ x, const float* __restrict__ M0,
    const float* __restrict__ Wk, const float* __restrict__ bk,
    const float* __restrict__ Wv, const float* __restrict__ bv,
    const float* __restrict__ a_in, const float* __restrict__ fall_in,
    float* __restrict__ out)
{
    __shared__ float sWk[D][D];   // 64 KB
    __shared__ float sWv[D][D];   // 64 KB
    __shared__ float sX[16][D];   // 8 KB
    __shared__ float sK[16][D];   // 8 KB
    __shared__ float sV[16][D];   // 8 KB
    __shared__ float sA[16];
    __shared__ float sBk[D];
    __shared__ float sBv[D];

    const int bh = blockIdx.x;    // b*H + h
    const int b  = bh >> 3;
    const int h  = bh & 7;
    const int ts = blockIdx.y;    // 0/1 t-split
    const int tid = threadIdx.x;

    // stage Wk_h, Wv_h (columns h*D .. h*D+127)
    #pragma unroll
    for (int q = 0; q < 16; ++q) {
        const int e = q * 256 + tid;      // float4 index, 0..4095
        const int d = e >> 5;
        const int c = (e & 31) * 4;
        *(float4*)&sWk[d][c] = *(const float4*)(Wk + (size_t)d * (D * H) + h * D + c);
        *(float4*)&sWv[d][c] = *(const float4*)(Wv + (size_t)d * (D * H) + h * D + c);
    }
    if (tid < D) {
        sBk[tid] = bk[h * D + tid];
        sBv[tid] = bv[h * D + tid];
    }

    float acc[8][8];
    #pragma unroll
    for (int u = 0; u < 8; ++u)
        #pragma unroll
        for (int v = 0; v < 8; ++v) acc[u][v] = 0.f;

    const int r  = tid >> 4;          // K/V-compute: row in tile
    const int i0 = (tid & 15) * 8;    // K/V-compute: 8 output cols
    const int mi = (tid >> 4) * 8;    // GEMM: 8 rows of C
    const int nj = (tid & 15) * 8;    // GEMM: 8 cols of C

    const float* xb   = x + (size_t)b * S * D;
    const float* arow = a_in + (size_t)bh * S;

    const int t_begin = ts * (S / 2);
    for (int t0 = t_begin; t0 < t_begin + S / 2; t0 += 16) {
        __syncthreads();
        // stage x tile (16 x 128), coalesced
        #pragma unroll
        for (int q = 0; q < 2; ++q) {
            const int e = q * 256 + tid;
            const int rr = e >> 5;
            const int c = (e & 31) * 4;
            *(float4*)&sX[rr][c] = *(const float4*)(xb + (size_t)(t0 + rr) * D + c);
        }
        if (tid < 16) sA[tid] = arow[t0 + tid];
        __syncthreads();

        // K'/V tile: each thread computes 8 K and 8 V entries of row r
        float ak[8], av[8];
        #pragma unroll
        for (int u = 0; u < 8; ++u) { ak[u] = 0.f; av[u] = 0.f; }
        for (int d = 0; d < D; ++d) {
            const float xv = sX[r][d];
            const float4 k0 = *(const float4*)&sWk[d][i0];
            const float4 k1 = *(const float4*)&sWk[d][i0 + 4];
            const float4 v0 = *(const float4*)&sWv[d][i0];
            const float4 v1 = *(const float4*)&sWv[d][i0 + 4];
            ak[0] += xv * k0.x; ak[1] += xv * k0.y; ak[2] += xv * k0.z; ak[3] += xv * k0.w;
            ak[4] += xv * k1.x; ak[5] += xv * k1.y; ak[6] += xv * k1.z; ak[7] += xv * k1.w;
            av[0] += xv * v0.x; av[1] += xv * v0.y; av[2] += xv * v0.z; av[3] += xv * v0.w;
            av[4] += xv * v1.x; av[5] += xv * v1.y; av[6] += xv * v1.z; av[7] += xv * v1.w;
        }
        const float sc = sA[r];
        #pragma unroll
        for (int u = 0; u < 8; ++u) {
            sK[r][i0 + u] = (ak[u] + sBk[i0 + u]) * sc;
            sV[r][i0 + u] = av[u] + sBv[i0 + u];
        }
        __syncthreads();

        // rank-16 outer-product update of the 8x8 per-thread tile
        for (int t = 0; t < 16; ++t) {
            const float4 ka = *(const float4*)&sK[t][mi];
            const float4 kb = *(const float4*)&sK[t][mi + 4];
            const float4 va = *(const float4*)&sV[t][nj];
            const float4 vb = *(const float4*)&sV[t][nj + 4];
            const float kk[8] = {ka.x, ka.y, ka.z, ka.w, kb.x, kb.y, kb.z, kb.w};
            const float vv[8] = {va.x, va.y, va.z, va.w, vb.x, vb.y, vb.z, vb.w};
            #pragma unroll
            for (int u = 0; u < 8; ++u)
                #pragma unroll
                for (int v = 0; v < 8; ++v) acc[u][v] += kk[u] * vv[v];
        }
    }

    // epilogue: ts==0 block also adds Fall*M0; both halves atomic-add into out
    const float fall = fall_in[bh];
    float* outp = out + (size_t)bh * D * D;
    const float* m0p = M0 + (size_t)bh * D * D;
    #pragma unroll
    for (int u = 0; u < 8; ++u) {
        #pragma unroll
        for (int v = 0; v < 8; ++v) {
            float val = acc[u][v];
            const size_t idx = (size_t)(mi + u) * D + (nj + v);
            if (ts == 0) val += fall * m0p[idx];
            unsafeAtomicAdd(&outp[idx], val);
        }
    }
}

extern "C" void kernel_launch(void* const* d_in, const int* in_sizes, int n_in,
                              void* d_out, int out_size, void* d_ws, size_t ws_size,
                              hipStream_t stream) {
    const float* x      = (const float*)d_in[0];
    const float* M0     = (const float*)d_in[1];
    const float* router = (const float*)d_in[2];
    const int*   mem_id = (const int*)d_in[3];
    const float* Wk     = (const float*)d_in[4];
    const float* bk     = (const float*)d_in[5];
    const float* Wv     = (const float*)d_in[6];
    const float* bv     = (const float*)d_in[7];
    const float* Wf     = (const float*)d_in[8];
    const float* bf     = (const float*)d_in[9];
    float* out = (float*)d_out;

    float* a_ws    = (float*)d_ws;                 // B*H*S floats
    float* fall_ws = a_ws + (size_t)B * H * S;     // B*H floats

    hipMemsetAsync(d_out, 0, (size_t)out_size * sizeof(float), stream);
    scan_kernel<<<B, 256, 0, stream>>>(x, router, mem_id, Wf, bf, a_ws, fall_ws);
    main_kernel<<<dim3(B * H, 2), 256, 0, stream>>>(x, M0, Wk, bk, Wv, bv,
                                                    a_ws, fall_ws, out);
}

// Round 2
// 157.392 us; speedup vs baseline: 5.4644x; 5.4644x over previous
//
#include <hip/hip_runtime.h>
#include <hip/hip_bf16.h>
#include <math.h>

constexpr int B = 16, S = 2048, D = 128, H = 8, NM = 4;
constexpr int KS = 4;          // K-split for G kernel (grid.y)
constexpr int TS = S / KS;     // 512 t per block
constexpr int BK = 64;         // t per staged iteration
constexpr int BKP = BK + 8;    // padded LDS row (bf16) = 72 el = 144 B (16B-aligned, conflict-free)

typedef __bf16  bf16x8 __attribute__((ext_vector_type(8)));
typedef float  f32x16 __attribute__((ext_vector_type(16)));

union PackU2 { __hip_bfloat162 h2[2]; uint2 u2; };
union PackU1 { __hip_bfloat162 h2;    unsigned int u; };

// ---------------------------------------------------------------------------
// A1: per (b, 128-row t-tile): stage x tile in LDS; compute f = sigmoid(x@Wf+bf)
// for all 8 heads; write fw[b][h][t]; write bf16 TRANSPOSED x -> xT[b][i][t]
// (t-contiguous, which is what the MFMA fragment loads need).
// ---------------------------------------------------------------------------
__global__ __launch_bounds__(256, 2) void a1_kernel(
    const float* __restrict__ x, const float* __restrict__ Wf,
    const float* __restrict__ bfv, float* __restrict__ fw,
    ushort* __restrict__ xTu)
{
    __shared__ float sX[128][132];   // 67.6 KB, +4 pad
    __shared__ float sWf[D * H];     // 4 KB

    const int b  = blockIdx.x >> 4;
    const int t0 = (blockIdx.x & 15) << 7;
    const int tid = threadIdx.x;

    for (int e = tid; e < D * H; e += 256) sWf[e] = Wf[e];

    #pragma unroll
    for (int q = 0; q < 16; ++q) {
        const int e = q * 256 + tid;
        const int row = e >> 5, c4 = (e & 31) * 4;
        *(float4*)&sX[row][c4] =
            *(const float4*)&x[((size_t)(b * S) + t0 + row) * D + c4];
    }
    __syncthreads();

    // ---- f projection: thread pair (r, d-half) ----
    {
        const int r = tid >> 1, dh = tid & 1;
        float acch[8] = {0.f,0.f,0.f,0.f,0.f,0.f,0.f,0.f};
        for (int d4 = 0; d4 < 64; d4 += 4) {
            const int d = dh * 64 + d4;
            const float4 xv = *(const float4*)&sX[r][d];
            const float xc[4] = {xv.x, xv.y, xv.z, xv.w};
            #pragma unroll
            for (int c = 0; c < 4; ++c) {
                const float4 wa = *(const float4*)&sWf[(d + c) * 8];
                const float4 wb = *(const float4*)&sWf[(d + c) * 8 + 4];
                acch[0] += xc[c] * wa.x; acch[1] += xc[c] * wa.y;
                acch[2] += xc[c] * wa.z; acch[3] += xc[c] * wa.w;
                acch[4] += xc[c] * wb.x; acch[5] += xc[c] * wb.y;
                acch[6] += xc[c] * wb.z; acch[7] += xc[c] * wb.w;
            }
        }
        #pragma unroll
        for (int hh = 0; hh < 8; ++hh) {
            const float tot = acch[hh] + __shfl_xor(acch[hh], 1);
            if (dh == 0) {
                const float z = tot + bfv[hh];
                fw[((size_t)(b * H + hh)) * S + t0 + r] = 1.f / (1.f + expf(-z));
            }
        }
    }

    // ---- transposed bf16 write: thread (i, t-half) ----
    {
        const int i = tid >> 1, th = tid & 1;
        ushort* dst = xTu + (size_t)(b * D + i) * S + t0 + th * 64;
        #pragma unroll
        for (int tq = 0; tq < 16; ++tq) {
            const int t = th * 64 + tq * 4;
            const float f0 = sX[t + 0][i], f1 = sX[t + 1][i];
            const float f2 = sX[t + 2][i], f3 = sX[t + 3][i];
            PackU2 pk;
            pk.h2[0] = __float22bfloat162_rn(make_float2(f0, f1));
            pk.h2[1] = __float22bfloat162_rn(make_float2(f2, f3));
            *(uint2*)&dst[tq * 4] = pk.u2;
        }
    }
}

// ---------------------------------------------------------------------------
// A2: per (b,h): suffix-product scan of f over S=2048; a[t] = w_t * prod_{u>t} f_u;
// fall = prod_t f_t; suma = sum_t a_t.
// ---------------------------------------------------------------------------
__global__ __launch_bounds__(256, 2) void a2_kernel(
    const float* __restrict__ fw, const float* __restrict__ router,
    const int* __restrict__ mem_id, float* __restrict__ a,
    float* __restrict__ fallp, float* __restrict__ sumap)
{
    __shared__ float sC[257];
    __shared__ float sR[4];
    const int bh = blockIdx.x, b = bh >> 3;
    const int tid = threadIdx.x;

    float f[8];
    const float* frow = fw + (size_t)bh * S + tid * 8;
    const float4 fa = *(const float4*)frow;
    const float4 fb = *(const float4*)(frow + 4);
    f[0]=fa.x; f[1]=fa.y; f[2]=fa.z; f[3]=fa.w;
    f[4]=fb.x; f[5]=fb.y; f[6]=fb.z; f[7]=fb.w;

    float p = f[0];
    #pragma unroll
    for (int u = 1; u < 8; ++u) p *= f[u];
    sC[tid] = p;
    __syncthreads();

    for (int off = 1; off < 256; off <<= 1) {
        const float v = (tid + off < 256) ? sC[tid + off] : 1.f;
        __syncthreads();
        sC[tid] *= v;
        __syncthreads();
    }
    const float E = (tid < 255) ? sC[tid + 1] : 1.f;
    const int mid = mem_id[0];

    float aa[8];
    float s = 1.f;
    #pragma unroll
    for (int u = 7; u >= 0; --u) { aa[u] = s * E; s *= f[u]; }

    float lsum = 0.f;
    #pragma unroll
    for (int u = 0; u < 8; ++u) {
        const int t = tid * 8 + u;
        const float w = router[((size_t)(b * S) + t) * NM + mid];
        const float av = aa[u] * w;
        a[(size_t)bh * S + t] = av;
        lsum += av;
    }
    for (int off = 32; off; off >>= 1) lsum += __shfl_down(lsum, off);
    if ((tid & 63) == 0) sR[tid >> 6] = lsum;
    __syncthreads();
    if (tid == 0) { sumap[bh] = sR[0] + sR[1] + sR[2] + sR[3]; fallp[bh] = sC[0]; }
}

// ---------------------------------------------------------------------------
// gemmG: per (bh, ks): G_part[ks][bh] = sum_{t in slice} a_t * x_t x_t^T via
// bf16 MFMA 32x32x16. A-operand = a-scaled x (scaled+rounded during staging),
// B-operand = raw bf16 x. Also accumulates s_vec = sum_t a_t x_t (atomics).
// LDS rows padded to 72 bf16 (144 B): uniform 8 words/bank for all b128 ops.
// ---------------------------------------------------------------------------
__global__ __launch_bounds__(256, 2) void gemmG_kernel(
    const ushort* __restrict__ xTu, const float* __restrict__ a,
    float* __restrict__ Gp, float* __restrict__ sv)
{
    __shared__ ushort sA[128][BKP];  // scaled   (18.4 KB)
    __shared__ ushort sXx[128][BKP]; // raw      (18.4 KB)
    __shared__ float  sAv[TS];       // a slice  (2 KB)
    __shared__ float  sRed[256];

    const int bh = blockIdx.x;
    const int b  = bh >> 3;
    const int ks = blockIdx.y;
    const int tid = threadIdx.x;

    const float* a_bh = a + (size_t)bh * S + ks * TS;
    sAv[tid]       = a_bh[tid];
    sAv[tid + 256] = a_bh[tid + 256];
    __syncthreads();

    const int th = tid >> 7;        // wave-uniform t-half
    const int i  = tid & 127;       // row
    const ushort* xrow = xTu + (size_t)(b * D + i) * S;

    const int lane = tid & 63, wid = tid >> 6;
    const int wrow = wid >> 1, wcol = wid & 1;
    const int m = lane & 31, half = lane >> 5;

    float svacc = 0.f;
    f32x16 acc00 = {}, acc01 = {}, acc10 = {}, acc11 = {};

    for (int it = 0; it < TS / BK; ++it) {
        const int tloc = it * BK + th * 32;
        uint4 r[4];
        #pragma unroll
        for (int u = 0; u < 4; ++u)
            r[u] = *(const uint4*)(xrow + ks * TS + tloc + u * 8);
        float av[32];
        #pragma unroll
        for (int q = 0; q < 8; ++q) {
            const float4 a4 = *(const float4*)&sAv[tloc + q * 4];
            av[q*4+0] = a4.x; av[q*4+1] = a4.y; av[q*4+2] = a4.z; av[q*4+3] = a4.w;
        }
        __syncthreads();   // previous iter's MFMA reads done
        #pragma unroll
        for (int u = 0; u < 4; ++u) {
            *(uint4*)&sXx[i][th * 32 + u * 8] = r[u];
            const unsigned int w[4] = {r[u].x, r[u].y, r[u].z, r[u].w};
            unsigned int o[4];
            #pragma unroll
            for (int q = 0; q < 4; ++q) {
                const float f0 = __uint_as_float(w[q] << 16);
                const float f1 = __uint_as_float(w[q] & 0xffff0000u);
                const float g0 = f0 * av[u * 8 + 2 * q];
                const float g1 = f1 * av[u * 8 + 2 * q + 1];
                svacc += g0 + g1;
                PackU1 pk;
                pk.h2 = __float22bfloat162_rn(make_float2(g0, g1));
                o[q] = pk.u;
            }
            *(uint4*)&sA[i][th * 32 + u * 8] = make_uint4(o[0], o[1], o[2], o[3]);
        }
        __syncthreads();
        #pragma unroll
        for (int kstep = 0; kstep < 4; ++kstep) {
            const int koff = kstep * 16 + half * 8;
            const bf16x8 a0 = *(const bf16x8*)&sA [wrow * 64 +      m][koff];
            const bf16x8 a1 = *(const bf16x8*)&sA [wrow * 64 + 32 + m][koff];
            const bf16x8 b0 = *(const bf16x8*)&sXx[wcol * 64 +      m][koff];
            const bf16x8 b1 = *(const bf16x8*)&sXx[wcol * 64 + 32 + m][koff];
            acc00 = __builtin_amdgcn_mfma_f32_32x32x16_bf16(a0, b0, acc00, 0, 0, 0);
            acc01 = __builtin_amdgcn_mfma_f32_32x32x16_bf16(a0, b1, acc01, 0, 0, 0);
            acc10 = __builtin_amdgcn_mfma_f32_32x32x16_bf16(a1, b0, acc10, 0, 0, 0);
            acc11 = __builtin_amdgcn_mfma_f32_32x32x16_bf16(a1, b1, acc11, 0, 0, 0);
        }
    }

    // C/D layout (measured m74/m101): col = lane&31, row = (r&3)+8*(r>>2)+4*half
    float* gp = Gp + (size_t)(ks * B * H + bh) * (D * D);
    #pragma unroll
    for (int rg = 0; rg < 16; ++rg) {
        const int rowl = (rg & 3) + 8 * (rg >> 2) + 4 * half;
        gp[(wrow * 64 +      rowl) * D + wcol * 64 +      m] = acc00[rg];
        gp[(wrow * 64 +      rowl) * D + wcol * 64 + 32 + m] = acc01[rg];
        gp[(wrow * 64 + 32 + rowl) * D + wcol * 64 +      m] = acc10[rg];
        gp[(wrow * 64 + 32 + rowl) * D + wcol * 64 + 32 + m] = acc11[rg];
    }

    sRed[tid] = svacc;
    __syncthreads();
    if (tid < 128)
        unsafeAtomicAdd(&sv[(size_t)bh * D + tid], sRed[tid] + sRed[tid + 128]);
}

// ---------------------------------------------------------------------------
// final: per (bh, col-half): C = Wk^T (G Wv) + u*bv^T + bk*w^T + suma*bk*bv^T
// + fall*M0. fp32 VALU; G symmetry used so all LDS reads are row-major float4.
// ---------------------------------------------------------------------------
__global__ __launch_bounds__(256, 1) void final_kernel(
    const float* __restrict__ Gp, const float* __restrict__ Wk,
    const float* __restrict__ bk, const float* __restrict__ Wv,
    const float* __restrict__ bv, const float* __restrict__ sv,
    const float* __restrict__ fallp, const float* __restrict__ sumap,
    const float* __restrict__ M0, float* __restrict__ out)
{
    __shared__ float sA[128][132];   // G, later P (cols 0..63)
    __shared__ float sB[128][132];   // Wv half, later Wk full
    __shared__ float sSv[128];

    const int bh = blockIdx.x >> 1, hf = blockIdx.x & 1;
    const int h  = bh & 7;
    const int tid = threadIdx.x;

    // G = sum of KS partial slices
    #pragma unroll
    for (int q = 0; q < 16; ++q) {
        const int flat = q * 256 + tid;
        const int row = flat >> 5, c4 = (flat & 31) * 4;
        const size_t off = (size_t)bh * (D * D) + row * D + c4;
        float4 g = *(const float4*)&Gp[off];
        #pragma unroll
        for (int k = 1; k < KS; ++k) {
            const float4 g2 = *(const float4*)&Gp[(size_t)k * B * H * D * D + off];
            g.x += g2.x; g.y += g2.y; g.z += g2.z; g.w += g2.w;
        }
        *(float4*)&sA[row][c4] = g;
    }
    #pragma unroll
    for (int q = 0; q < 8; ++q) {
        const int flat = q * 256 + tid;
        const int l = flat >> 4, c4 = (flat & 15) * 4;
        *(float4*)&sB[l][c4] =
            *(const float4*)&Wv[(size_t)l * (D * H) + h * D + hf * 64 + c4];
    }
    if (tid < 128) sSv[tid] = sv[(size_t)bh * D + tid];
    __syncthreads();

    const int r0 = (tid >> 3) * 4, c0 = (tid & 7) * 8;

    // phase 1: P[r][c] = sum_l G[r][l] Wv[l][c]  (reads G[l][r] via symmetry)
    float P[4][8] = {};
    float wv8[8] = {};
    for (int l = 0; l < 128; ++l) {
        const float4 g  = *(const float4*)&sA[l][r0];
        const float4 w0 = *(const float4*)&sB[l][c0];
        const float4 w1 = *(const float4*)&sB[l][c0 + 4];
        const float sl = sSv[l];
        const float gg[4] = {g.x, g.y, g.z, g.w};
        const float ww[8] = {w0.x,w0.y,w0.z,w0.w,w1.x,w1.y,w1.z,w1.w};
        #pragma unroll
        for (int dr = 0; dr < 4; ++dr)
            #pragma unroll
            for (int dc = 0; dc < 8; ++dc) P[dr][dc] += gg[dr] * ww[dc];
        #pragma unroll
        for (int dc = 0; dc < 8; ++dc) wv8[dc] += sl * ww[dc];
    }
    __syncthreads();   // done reading G and Wv

    // phase 2: P -> sA (cols 0..63); Wk(full) -> sB
    #pragma unroll
    for (int dr = 0; dr < 4; ++dr) {
        *(float4*)&sA[r0 + dr][c0]     = make_float4(P[dr][0], P[dr][1], P[dr][2], P[dr][3]);
        *(float4*)&sA[r0 + dr][c0 + 4] = make_float4(P[dr][4], P[dr][5], P[dr][6], P[dr][7]);
    }
    #pragma unroll
    for (int q = 0; q < 16; ++q) {
        const int flat = q * 256 + tid;
        const int k = flat >> 5, c4 = (flat & 31) * 4;
        *(float4*)&sB[k][c4] = *(const float4*)&Wk[(size_t)k * (D * H) + h * D + c4];
    }
    __syncthreads();

    // phase 3: C[i][c] = sum_k Wk[k][i] P[k][c];  u_i = sum_k Wk[k][i] sv[k]
    float C[4][8] = {};
    float u4[4] = {};
    for (int k = 0; k < 128; ++k) {
        const float4 wk = *(const float4*)&sB[k][r0];
        const float4 p0 = *(const float4*)&sA[k][c0];
        const float4 p1 = *(const float4*)&sA[k][c0 + 4];
        const float svk = sSv[k];
        const float wkk[4] = {wk.x, wk.y, wk.z, wk.w};
        const float pp[8] = {p0.x,p0.y,p0.z,p0.w,p1.x,p1.y,p1.z,p1.w};
        #pragma unroll
        for (int di = 0; di < 4; ++di) {
            #pragma unroll
            for (int dc = 0; dc < 8; ++dc) C[di][dc] += wkk[di] * pp[dc];
            u4[di] += wkk[di] * svk;
        }
    }

    const float fallv = fallp[bh], sumav = sumap[bh];
    float bkv[4], bvv[8];
    #pragma unroll
    for (int di = 0; di < 4; ++di) bkv[di] = bk[h * D + r0 + di];
    #pragma unroll
    for (int dc = 0; dc < 8; ++dc) bvv[dc] = bv[h * D + hf * 64 + c0 + dc];

    const float* m0p = M0 + (size_t)bh * (D * D);
    float* op = out + (size_t)bh * (D * D);
    #pragma unroll
    for (int di = 0; di < 4; ++di)
        #pragma unroll
        for (int dc = 0; dc < 8; ++dc) {
            const size_t idx = (size_t)(r0 + di) * D + hf * 64 + c0 + dc;
            op[idx] = C[di][dc] + u4[di] * bvv[dc] + bkv[di] * wv8[dc]
                    + sumav * bkv[di] * bvv[dc] + fallv * m0p[idx];
        }
}

extern "C" void kernel_launch(void* const* d_in, const int* in_sizes, int n_in,
                              void* d_out, int out_size, void* d_ws, size_t ws_size,
                              hipStream_t stream) {
    const float* x      = (const float*)d_in[0];
    const float* M0     = (const float*)d_in[1];
    const float* router = (const float*)d_in[2];
    const int*   mem_id = (const int*)d_in[3];
    const float* Wk     = (const float*)d_in[4];
    const float* bk     = (const float*)d_in[5];
    const float* Wv     = (const float*)d_in[6];
    const float* bv     = (const float*)d_in[7];
    const float* Wf     = (const float*)d_in[8];
    const float* bf     = (const float*)d_in[9];
    float* out = (float*)d_out;

    char* ws = (char*)d_ws;
    ushort* xTu  = (ushort*)ws;                              // 8 MB  bf16 x^T
    float*  fw   = (float*)(ws + (8u << 20));                // 1 MB  f gates
    float*  a    = (float*)(ws + (9u << 20));                // 1 MB  a_t
    float*  sv   = (float*)(ws + (10u << 20));               // 64 KB s_vec
    float*  fall = (float*)(ws + (10u << 20) + (1u << 16));  // fall
    float*  suma = (float*)(ws + (10u << 20) + (1u << 16) + 4096); // suma
    float*  Gp   = (float*)(ws + (11u << 20));               // 32 MB G partials

    hipMemsetAsync(sv, 0, (size_t)B * H * D * sizeof(float), stream);
    a1_kernel<<<256, 256, 0, stream>>>(x, Wf, bf, fw, xTu);
    a2_kernel<<<B * H, 256, 0, stream>>>(fw, router, mem_id, a, fall, suma);
    gemmG_kernel<<<dim3(B * H, KS), 256, 0, stream>>>(xTu, a, Gp, sv);
    final_kernel<<<2 * B * H, 256, 0, stream>>>(Gp, Wk, bk, Wv, bv, sv,
                                                fall, suma, M0, out);
}